// Round 9
// baseline (812.218 us; speedup 1.0000x reference)
//
#include <hip/hip_runtime.h>
#include <hip/hip_bf16.h>

#define HH   128
#define EMB  300
#define SEQ  1024
#define BS   64
#define NG   384   // 3*H
#define NCHUNK 8   // col_sum t-chunks

typedef __attribute__((ext_vector_type(8))) short  bf16x8;
typedef __attribute__((ext_vector_type(4))) float  f32x4;
typedef _Float16 f16x2 __attribute__((ext_vector_type(2)));
typedef _Float16 f16x8 __attribute__((ext_vector_type(8)));

__device__ __forceinline__ unsigned short f2bf(float f) {
    unsigned int u = __float_as_uint(f);
    unsigned int r = (u + 0x7fffu + ((u >> 16) & 1u)) >> 16;   // RNE
    return (unsigned short)r;
}
__device__ __forceinline__ float fexp(float x) { return __builtin_amdgcn_exp2f(x * 1.44269504088896f); }
__device__ __forceinline__ float fsig(float x) { return __builtin_amdgcn_rcpf(1.f + fexp(-x)); }
__device__ __forceinline__ float ftanh(float x){ return __builtin_amdgcn_rcpf(1.f + fexp(-2.f*x)) * 2.f - 1.f; }

// LDS-only barrier: drains LDS ops but leaves global loads in flight.
#define BAR_LDS() asm volatile("s_waitcnt lgkmcnt(0)\n\ts_barrier" ::: "memory")

// ---------------------------------------------------------------------------
// gi[r, j] = (sum_e X[r,e]*mask[r]*W[j,e]) + bias[j]  (+ bhh[j] for j<2H:
// the r/z recurrent biases are folded in here so the scan skips two adds)
// ---------------------------------------------------------------------------
__global__ __launch_bounds__(256) void gi_gemm(const float* __restrict__ X,
                                               const float* __restrict__ mask,
                                               const float* __restrict__ W,
                                               const float* __restrict__ bias,
                                               const float* __restrict__ bhh2,
                                               float* __restrict__ out) {
    __shared__ __align__(16) unsigned short As[128 * 32];
    __shared__ __align__(16) unsigned short Bs[128 * 32];
    const int m0   = blockIdx.x * 128;
    const int n0   = blockIdx.y * 128;
    const int tid  = threadIdx.x;
    const int row  = tid >> 1;            // 0..127
    const int seg  = tid & 1;             // 16-col half
    const int wave = tid >> 6;
    const int lane = tid & 63;
    const int wr   = wave >> 1, wc = wave & 1;
    const int r16  = lane & 15, kg = lane >> 4;

    f32x4 acc[4][4];
    #pragma unroll
    for (int m = 0; m < 4; ++m)
        #pragma unroll
        for (int n = 0; n < 4; ++n) acc[m][n] = (f32x4){0.f,0.f,0.f,0.f};

    const float mrow = mask[m0 + row];

    for (int k0 = 0; k0 < 320; k0 += 32) {
        // ---- stage A (x * mask -> bf16) ----
        {
            const float* src = X + (size_t)(m0 + row) * EMB + k0 + seg * 16;
            unsigned short tmp[16];
            if (k0 + seg * 16 + 15 < EMB) {
                #pragma unroll
                for (int i = 0; i < 4; ++i) {
                    float4 v = ((const float4*)src)[i];
                    tmp[i*4+0] = f2bf(v.x * mrow);
                    tmp[i*4+1] = f2bf(v.y * mrow);
                    tmp[i*4+2] = f2bf(v.z * mrow);
                    tmp[i*4+3] = f2bf(v.w * mrow);
                }
            } else {
                #pragma unroll
                for (int i = 0; i < 16; ++i) {
                    int c = k0 + seg * 16 + i;
                    float v = (c < EMB) ? src[i] : 0.f;
                    tmp[i] = f2bf(v * mrow);
                }
            }
            uint4* dst = (uint4*)&As[row * 32 + seg * 16];
            dst[0] = ((const uint4*)tmp)[0];
            dst[1] = ((const uint4*)tmp)[1];
        }
        // ---- stage B (W -> bf16) ----
        {
            const float* src = W + (size_t)(n0 + row) * EMB + k0 + seg * 16;
            unsigned short tmp[16];
            if (k0 + seg * 16 + 15 < EMB) {
                #pragma unroll
                for (int i = 0; i < 4; ++i) {
                    float4 v = ((const float4*)src)[i];
                    tmp[i*4+0] = f2bf(v.x);
                    tmp[i*4+1] = f2bf(v.y);
                    tmp[i*4+2] = f2bf(v.z);
                    tmp[i*4+3] = f2bf(v.w);
                }
            } else {
                #pragma unroll
                for (int i = 0; i < 16; ++i) {
                    int c = k0 + seg * 16 + i;
                    float v = (c < EMB) ? src[i] : 0.f;
                    tmp[i] = f2bf(v);
                }
            }
            uint4* dst = (uint4*)&Bs[row * 32 + seg * 16];
            dst[0] = ((const uint4*)tmp)[0];
            dst[1] = ((const uint4*)tmp)[1];
        }
        __syncthreads();

        bf16x8 a[4], bfr[4];
        #pragma unroll
        for (int m = 0; m < 4; ++m)
            a[m] = *(const bf16x8*)&As[(wr * 64 + m * 16 + r16) * 32 + kg * 8];
        #pragma unroll
        for (int n = 0; n < 4; ++n)
            bfr[n] = *(const bf16x8*)&Bs[(wc * 64 + n * 16 + r16) * 32 + kg * 8];
        #pragma unroll
        for (int m = 0; m < 4; ++m)
            #pragma unroll
            for (int n = 0; n < 4; ++n)
                acc[m][n] = __builtin_amdgcn_mfma_f32_16x16x32_bf16(a[m], bfr[n], acc[m][n], 0, 0, 0);
        __syncthreads();
    }

    // ---- epilogue ----
    #pragma unroll
    for (int m = 0; m < 4; ++m) {
        const int rowb = m0 + wr * 64 + m * 16 + (lane >> 4) * 4;
        #pragma unroll
        for (int n = 0; n < 4; ++n) {
            const int col = n0 + wc * 64 + n * 16 + r16;
            const float bj = bias[col] + (col < 2 * HH ? bhh2[col] : 0.f);
            #pragma unroll
            for (int q = 0; q < 4; ++q)
                out[(size_t)(rowb + q) * NG + col] = acc[m][n][q] + bj;
        }
    }
}

// ---------------------------------------------------------------------------
// partial column sums: spart[(b*NCHUNK + c)][e] = sum over 128 t's
// ---------------------------------------------------------------------------
__global__ __launch_bounds__(320) void col_sum(const float* __restrict__ X,
                                               const float* __restrict__ mask,
                                               float* __restrict__ spart) {
    const int b = blockIdx.x, c = blockIdx.y;
    const int e = threadIdx.x;
    if (e >= EMB) return;
    const int tchunk = SEQ / NCHUNK;   // 128
    float acc = 0.f;
    const float* xb = X + ((size_t)b * SEQ + (size_t)c * tchunk) * EMB;
    const float* mb = mask + (size_t)b * SEQ + (size_t)c * tchunk;
    for (int t = 0; t < tchunk; ++t)
        acc += xb[(size_t)t * EMB + e] * mb[t];
    spart[((size_t)b * NCHUNK + c) * EMB + e] = acc;
}

// ---------------------------------------------------------------------------
// forward GRU scan, batched via MFMA: 4 blocks x 16 batches, 512 threads.
// Per step: GH = W_hh(384x128) . H(128x16) with mfma_f32_16x16x32_f16.
// Wave w owns m-tiles {w, w+8, w+16} -> lane holds r,z,n for the SAME
// (j,batch): gate math is thread-local. C layout (verified in gi_gemm):
// row = j = w*16 + (lane>>4)*4 + q (A-side = W rows), col = batch = lane&15
// (B-side = h columns). W_hh stays in VGPRs as f16 A-frags; h is f16 in LDS
// [16][136] (double-buffered, padded); h_new = one ds_write_b64 per lane.
// gi loaded as 3 float4/thread, prefetched 2 steps ahead; BAR_LDS keeps
// those loads in flight across the single per-step barrier.
// ---------------------------------------------------------------------------
__global__ __launch_bounds__(512, 1) void gru_scan(const float* __restrict__ gi,
                                                   const float* __restrict__ Whh,
                                                   const float* __restrict__ bhh,
                                                   float* __restrict__ hout) {
    const int tid  = threadIdx.x;
    const int w    = tid >> 6;           // wave 0..7
    const int lane = tid & 63;
    const int m16  = lane & 15;          // A-row within tile AND batch col
    const int kg   = lane >> 4;          // k-group (A/B) AND C row-group
    const int bg   = blockIdx.x * 16 + m16;   // global batch (C col side)
    const int j0   = w * 16 + kg * 4;    // first of this lane's 4 output rows

    __shared__ _Float16 hl[2][16][136];  // [parity][batch][h], 16B-aligned rows

    // ---- A-frags: W_hh rows for gates r/z/n, 4 k-steps, f16 ----
    f16x8 wfr[4], wfz[4], wfn[4];
    {
        const float* base = Whh + (size_t)(w * 16 + m16) * HH + kg * 8;
        #pragma unroll
        for (int ks = 0; ks < 4; ++ks) {
            float4 a0 = *(const float4*)(base + ks * 32);
            float4 a1 = *(const float4*)(base + ks * 32 + 4);
            wfr[ks] = (f16x8){(_Float16)a0.x,(_Float16)a0.y,(_Float16)a0.z,(_Float16)a0.w,
                              (_Float16)a1.x,(_Float16)a1.y,(_Float16)a1.z,(_Float16)a1.w};
            a0 = *(const float4*)(base + HH * HH + ks * 32);
            a1 = *(const float4*)(base + HH * HH + ks * 32 + 4);
            wfz[ks] = (f16x8){(_Float16)a0.x,(_Float16)a0.y,(_Float16)a0.z,(_Float16)a0.w,
                              (_Float16)a1.x,(_Float16)a1.y,(_Float16)a1.z,(_Float16)a1.w};
            a0 = *(const float4*)(base + 2 * HH * HH + ks * 32);
            a1 = *(const float4*)(base + 2 * HH * HH + ks * 32 + 4);
            wfn[ks] = (f16x8){(_Float16)a0.x,(_Float16)a0.y,(_Float16)a0.z,(_Float16)a0.w,
                              (_Float16)a1.x,(_Float16)a1.y,(_Float16)a1.z,(_Float16)a1.w};
        }
    }
    // n-gate recurrent bias (r/z biases were folded into gi by gi_gemm)
    float bn[4];
    #pragma unroll
    for (int q = 0; q < 4; ++q) bn[q] = bhh[2 * HH + j0 + q];

    // ---- zero h state ----
    for (int i = tid; i < 16 * 136; i += 512) ((unsigned short*)hl[0])[i] = 0;
    float hq[4] = {0.f, 0.f, 0.f, 0.f};

    // ---- gi prefetch: 3 float4 per thread per step, depth 2 ----
    const float* p0 = gi + ((size_t)bg * SEQ + 0) * NG + j0;
    const float* p1 = gi + ((size_t)bg * SEQ + 1) * NG + j0;
    f32x4 Gr0 = *(const f32x4*)(p0);
    f32x4 Gz0 = *(const f32x4*)(p0 + HH);
    f32x4 Gn0 = *(const f32x4*)(p0 + 2 * HH);
    f32x4 Gr1 = *(const f32x4*)(p1);
    f32x4 Gz1 = *(const f32x4*)(p1 + HH);
    f32x4 Gn1 = *(const f32x4*)(p1 + 2 * HH);
    p0 += 2 * NG; p1 += 2 * NG;
    BAR_LDS();

    // NOTE: prefetch in the final iterations reads past gi's end into the
    // spart/hf/hb scratch regions (allocated) — loaded but never consumed.
#define GRU_BODY(P, GR, GZ, GN, PP)                                            \
    {                                                                          \
        f32x4 aR = (f32x4){0.f,0.f,0.f,0.f};                                   \
        f32x4 aZ = (f32x4){0.f,0.f,0.f,0.f};                                   \
        f32x4 aN = (f32x4){0.f,0.f,0.f,0.f};                                   \
        _Pragma("unroll")                                                      \
        for (int ks = 0; ks < 4; ++ks) {                                       \
            f16x8 hbf = *(const f16x8*)&hl[P][m16][ks * 32 + kg * 8];          \
            aR = __builtin_amdgcn_mfma_f32_16x16x32_f16(wfr[ks], hbf, aR, 0, 0, 0); \
            aZ = __builtin_amdgcn_mfma_f32_16x16x32_f16(wfz[ks], hbf, aZ, 0, 0, 0); \
            aN = __builtin_amdgcn_mfma_f32_16x16x32_f16(wfn[ks], hbf, aN, 0, 0, 0); \
        }                                                                      \
        union { _Float16 h[4]; uint2 u; } HU;                                  \
        _Pragma("unroll")                                                      \
        for (int q = 0; q < 4; ++q) {                                          \
            const float r  = fsig(GR[q] + aR[q]);                              \
            const float zz = fsig(GZ[q] + aZ[q]);                              \
            const float nn = ftanh(GN[q] + r * (aN[q] + bn[q]));               \
            hq[q] = nn + zz * (hq[q] - nn);                                    \
            HU.h[q] = (_Float16)hq[q];                                         \
        }                                                                      \
        *(uint2*)&hl[P ^ 1][m16][j0] = HU.u;                                   \
        GR = *(const f32x4*)(PP);                                              \
        GZ = *(const f32x4*)(PP + HH);                                         \
        GN = *(const f32x4*)(PP + 2 * HH);                                     \
        PP += 2 * NG;                                                          \
        BAR_LDS();                                                             \
    }

    for (int it = 0; it < SEQ / 2; ++it) {
        GRU_BODY(0, Gr0, Gz0, Gn0, p0)
        GRU_BODY(1, Gr1, Gz1, Gn1, p1)
    }
#undef GRU_BODY

    *(float4*)&hout[(size_t)bg * HH + j0] = (float4){hq[0], hq[1], hq[2], hq[3]};
}

// ---------------------------------------------------------------------------
__global__ __launch_bounds__(384) void gru_bwd(const float* __restrict__ X,
                                               const float* __restrict__ mask,
                                               const float* __restrict__ Wih,
                                               const float* __restrict__ bih,
                                               const float* __restrict__ bhh,
                                               float* __restrict__ hout) {
    const int b = blockIdx.x, j = threadIdx.x;
    __shared__ float gib[NG];
    const float* xr = X + ((size_t)b * SEQ + (SEQ - 1)) * EMB;
    const float  mv = mask[(size_t)b * SEQ + SEQ - 1];
    const float* wr_ = Wih + (size_t)j * EMB;
    float acc = 0.f;
    for (int e = 0; e < EMB; ++e) acc += xr[e] * wr_[e];
    gib[j] = acc * mv + bih[j];
    __syncthreads();
    if (j < HH) {
        const float r = fsig(gib[j] + bhh[j]);
        const float z = fsig(gib[j + HH] + bhh[j + HH]);
        const float n = ftanh(gib[j + 2 * HH] + r * bhh[j + 2 * HH]);
        hout[b * HH + j] = (1.f - z) * n;
    }
}

// ---------------------------------------------------------------------------
__global__ __launch_bounds__(128) void mlp(const float* __restrict__ hf,
                                           const float* __restrict__ hb,
                                           const float* __restrict__ spart,
                                           const float* __restrict__ W1, const float* __restrict__ b1,
                                           const float* __restrict__ W2, const float* __restrict__ b2,
                                           const float* __restrict__ W3, const float* __restrict__ b3,
                                           float* __restrict__ out) {
    const int b = blockIdx.x, j = threadIdx.x;
    __shared__ float zin[2 * HH + EMB];   // 556
    __shared__ float l1[128];
    __shared__ float l2[64];
    zin[j]      = hf[b * HH + j];
    zin[HH + j] = hb[b * HH + j];
    for (int e = j; e < EMB; e += 128) {
        float v = 0.f;
        #pragma unroll
        for (int c = 0; c < NCHUNK; ++c)
            v += spart[((size_t)b * NCHUNK + c) * EMB + e];
        zin[2 * HH + e] = v * v;
    }
    __syncthreads();
    {
        float a = b1[j];
        const float* w = W1 + (size_t)j * (2 * HH + EMB);
        for (int i = 0; i < 2 * HH + EMB; ++i) a += zin[i] * w[i];
        l1[j] = fmaxf(a, 0.f);
    }
    __syncthreads();
    if (j < 64) {
        float a = b2[j];
        const float* w = W2 + (size_t)j * 128;
        for (int i = 0; i < 128; ++i) a += l1[i] * w[i];
        l2[j] = fmaxf(a, 0.f);
    }
    __syncthreads();
    if (j < 23) {
        float a = b3[j];
        const float* w = W3 + (size_t)j * 64;
        for (int i = 0; i < 64; ++i) a += l2[i] * w[i];
        out[b * 23 + j] = a;
    }
}

// ---------------------------------------------------------------------------
extern "C" void kernel_launch(void* const* d_in, const int* in_sizes, int n_in,
                              void* d_out, int out_size, void* d_ws, size_t ws_size,
                              hipStream_t stream) {
    const float* x     = (const float*)d_in[0];
    const float* mask  = (const float*)d_in[2];
    const float* Wih_f = (const float*)d_in[3];
    const float* Whh_f = (const float*)d_in[4];
    const float* bih_f = (const float*)d_in[5];
    const float* bhh_f = (const float*)d_in[6];
    const float* Wih_b = (const float*)d_in[7];
    const float* bih_b = (const float*)d_in[9];
    const float* bhh_b = (const float*)d_in[10];
    const float* W1 = (const float*)d_in[11];
    const float* b1 = (const float*)d_in[12];
    const float* W2 = (const float*)d_in[13];
    const float* b2 = (const float*)d_in[14];
    const float* W3 = (const float*)d_in[15];
    const float* b3 = (const float*)d_in[16];
    float* out = (float*)d_out;

    float* gi    = (float*)d_ws;                          // 64*1024*384 f32
    float* spart = gi + (size_t)BS * SEQ * NG;            // 64*8*300
    float* hf    = spart + (size_t)BS * NCHUNK * EMB;     // 64*128
    float* hb    = hf + BS * HH;                          // 64*128

    gi_gemm<<<dim3(512, 3), dim3(256), 0, stream>>>(x, mask, Wih_f, bih_f, bhh_f, gi);
    col_sum<<<dim3(BS, NCHUNK), dim3(320), 0, stream>>>(x, mask, spart);
    gru_scan<<<dim3(4), dim3(512), 0, stream>>>(gi, Whh_f, bhh_f, hf);
    gru_bwd<<<dim3(BS), dim3(384), 0, stream>>>(x, mask, Wih_b, bih_b, bhh_b, hb);
    mlp<<<dim3(BS), dim3(128), 0, stream>>>(hf, hb, spart, W1, b1, W2, b2, W3, b3, out);
}

// Round 10
// 579.043 us; speedup vs baseline: 1.4027x; 1.4027x over previous
//
#include <hip/hip_runtime.h>
#include <hip/hip_bf16.h>

#define HH   128
#define EMB  300
#define SEQ  1024
#define BS   64
#define NG   384   // 3*H
#define NCHUNK 8   // col_sum t-chunks

typedef __attribute__((ext_vector_type(8))) short  bf16x8;
typedef __attribute__((ext_vector_type(4))) float  f32x4;
typedef _Float16 f16x2 __attribute__((ext_vector_type(2)));

__device__ __forceinline__ unsigned short f2bf(float f) {
    unsigned int u = __float_as_uint(f);
    unsigned int r = (u + 0x7fffu + ((u >> 16) & 1u)) >> 16;   // RNE
    return (unsigned short)r;
}
__device__ __forceinline__ float bf2f(unsigned short u) {
    return __uint_as_float((unsigned int)u << 16);
}
__device__ __forceinline__ float fexp(float x) { return __builtin_amdgcn_exp2f(x * 1.44269504088896f); }
__device__ __forceinline__ float fsig(float x) { return __builtin_amdgcn_rcpf(1.f + fexp(-x)); }
__device__ __forceinline__ float ftanh(float x){ return __builtin_amdgcn_rcpf(1.f + fexp(-2.f*x)) * 2.f - 1.f; }

// add the value from the adjacent lane (lane^1) via DPP quad_perm(1,0,3,2)
__device__ __forceinline__ float dpp_pair_add(float x) {
    int y = __builtin_amdgcn_mov_dpp(__float_as_int(x), 0xB1, 0xF, 0xF, true);
    return x + __int_as_float(y);
}

// LDS-only barrier: drains LDS ops but leaves global loads in flight.
#define BAR_LDS() asm volatile("s_waitcnt lgkmcnt(0)\n\ts_barrier" ::: "memory")

// ---------------------------------------------------------------------------
// gi[r, j] = bf16( (sum_e X[r,e]*mask[r]*W[j,e]) + bias[j] + (j<2H ? bhh[j]:0) )
// Single X pass: block = 128 M-rows x FULL N=384, 512 threads (8 waves 2m x 4n).
// ---------------------------------------------------------------------------
__global__ __launch_bounds__(512) void gi_gemm(const float* __restrict__ X,
                                               const float* __restrict__ mask,
                                               const float* __restrict__ W,
                                               const float* __restrict__ bias,
                                               const float* __restrict__ bhh2,
                                               unsigned short* __restrict__ out) {
    __shared__ __align__(16) unsigned short As[128 * 32];
    __shared__ __align__(16) unsigned short Bs[384 * 32];
    const int m0   = blockIdx.x * 128;
    const int tid  = threadIdx.x;
    const int row  = tid >> 2;            // 0..127
    const int seg  = tid & 3;             // 8-col segment
    const int wave = tid >> 6;            // 0..7
    const int lane = tid & 63;
    const int wm   = wave >> 2;           // 0..1 (64 M rows each)
    const int wn   = wave & 3;            // 0..3 (96 N cols each)
    const int r16  = lane & 15, kg = lane >> 4;

    f32x4 acc[4][6];
    #pragma unroll
    for (int m = 0; m < 4; ++m)
        #pragma unroll
        for (int n = 0; n < 6; ++n) acc[m][n] = (f32x4){0.f,0.f,0.f,0.f};

    const float mrow = mask[m0 + row];

    for (int k0 = 0; k0 < 320; k0 += 32) {
        // ---- stage A (x * mask -> bf16), 8 cols per thread ----
        {
            const float* src = X + (size_t)(m0 + row) * EMB + k0 + seg * 8;
            unsigned short tmp[8];
            if (k0 + seg * 8 + 7 < EMB) {
                float4 v0 = ((const float4*)src)[0];
                float4 v1 = ((const float4*)src)[1];
                tmp[0]=f2bf(v0.x*mrow); tmp[1]=f2bf(v0.y*mrow);
                tmp[2]=f2bf(v0.z*mrow); tmp[3]=f2bf(v0.w*mrow);
                tmp[4]=f2bf(v1.x*mrow); tmp[5]=f2bf(v1.y*mrow);
                tmp[6]=f2bf(v1.z*mrow); tmp[7]=f2bf(v1.w*mrow);
            } else {
                #pragma unroll
                for (int i = 0; i < 8; ++i) {
                    int c = k0 + seg * 8 + i;
                    float v = (c < EMB) ? src[i] : 0.f;
                    tmp[i] = f2bf(v * mrow);
                }
            }
            *(uint4*)&As[row * 32 + seg * 8] = *(const uint4*)tmp;
        }
        // ---- stage B (W -> bf16): 3 row-groups per thread ----
        #pragma unroll
        for (int r3 = 0; r3 < 3; ++r3) {
            const int rowb = row + r3 * 128;
            const float* src = W + (size_t)rowb * EMB + k0 + seg * 8;
            unsigned short tmp[8];
            if (k0 + seg * 8 + 7 < EMB) {
                float4 v0 = ((const float4*)src)[0];
                float4 v1 = ((const float4*)src)[1];
                tmp[0]=f2bf(v0.x); tmp[1]=f2bf(v0.y); tmp[2]=f2bf(v0.z); tmp[3]=f2bf(v0.w);
                tmp[4]=f2bf(v1.x); tmp[5]=f2bf(v1.y); tmp[6]=f2bf(v1.z); tmp[7]=f2bf(v1.w);
            } else {
                #pragma unroll
                for (int i = 0; i < 8; ++i) {
                    int c = k0 + seg * 8 + i;
                    float v = (c < EMB) ? src[i] : 0.f;
                    tmp[i] = f2bf(v);
                }
            }
            *(uint4*)&Bs[rowb * 32 + seg * 8] = *(const uint4*)tmp;
        }
        __syncthreads();

        bf16x8 a[4], bfr[6];
        #pragma unroll
        for (int m = 0; m < 4; ++m)
            a[m] = *(const bf16x8*)&As[(wm * 64 + m * 16 + r16) * 32 + kg * 8];
        #pragma unroll
        for (int n = 0; n < 6; ++n)
            bfr[n] = *(const bf16x8*)&Bs[(wn * 96 + n * 16 + r16) * 32 + kg * 8];
        #pragma unroll
        for (int m = 0; m < 4; ++m)
            #pragma unroll
            for (int n = 0; n < 6; ++n)
                acc[m][n] = __builtin_amdgcn_mfma_f32_16x16x32_bf16(a[m], bfr[n], acc[m][n], 0, 0, 0);
        __syncthreads();
    }

    // ---- epilogue: bf16 gi with r/z recurrent bias folded ----
    #pragma unroll
    for (int m = 0; m < 4; ++m) {
        const int rowb = m0 + wm * 64 + m * 16 + kg * 4;
        #pragma unroll
        for (int n = 0; n < 6; ++n) {
            const int col = wn * 96 + n * 16 + r16;
            const float bj = bias[col] + (col < 2 * HH ? bhh2[col] : 0.f);
            #pragma unroll
            for (int q = 0; q < 4; ++q)
                out[(size_t)(rowb + q) * NG + col] = f2bf(acc[m][n][q] + bj);
        }
    }
}

// ---------------------------------------------------------------------------
// partial column sums: spart[(b*NCHUNK + c)][e] = sum over 128 t's
// ---------------------------------------------------------------------------
__global__ __launch_bounds__(320) void col_sum(const float* __restrict__ X,
                                               const float* __restrict__ mask,
                                               float* __restrict__ spart) {
    const int b = blockIdx.x, c = blockIdx.y;
    const int e = threadIdx.x;
    if (e >= EMB) return;
    const int tchunk = SEQ / NCHUNK;   // 128
    float acc = 0.f;
    const float* xb = X + ((size_t)b * SEQ + (size_t)c * tchunk) * EMB;
    const float* mb = mask + (size_t)b * SEQ + (size_t)c * tchunk;
    for (int t = 0; t < tchunk; ++t)
        acc += xb[(size_t)t * EMB + e] * mb[t];
    spart[((size_t)b * NCHUNK + c) * EMB + e] = acc;
}

// ---------------------------------------------------------------------------
// forward GRU scan (r6 structure): 256 threads, output j = tid>>1, k-half =
// tid&1 (adjacent lanes, DPP pair-add combine). One barrier per step
// (double-buffered f16 h). gi is bf16 with r/z biases pre-folded; prefetched
// 4 steps ahead via incremental pointers; BAR_LDS keeps loads in flight.
// ---------------------------------------------------------------------------
__global__ __launch_bounds__(256, 1) void gru_scan(const unsigned short* __restrict__ gi,
                                                   const float* __restrict__ Whh,
                                                   const float* __restrict__ bhh,
                                                   float* __restrict__ hout) {
    const int b    = blockIdx.x;
    const int tid  = threadIdx.x;
    const int j    = tid >> 1;           // 0..127 output index
    const int half = tid & 1;            // k-half (adjacent lanes)
    __shared__ __align__(16) _Float16 hb[2][HH];

    // ---- weights: rows j, j+HH, j+2HH, cols [half*64, half*64+64) ----
    f16x2 wr_[32], wz_[32], wn_[32];
    {
        const float2* r0 = (const float2*)(Whh + (size_t)j * HH            + half * 64);
        const float2* r1 = (const float2*)(Whh + (size_t)(j + HH) * HH     + half * 64);
        const float2* r2 = (const float2*)(Whh + (size_t)(j + 2 * HH) * HH + half * 64);
        #pragma unroll
        for (int i = 0; i < 32; ++i) {
            float2 a = r0[i], c = r1[i], d = r2[i];
            wr_[i] = (f16x2){(_Float16)a.x, (_Float16)a.y};
            wz_[i] = (f16x2){(_Float16)c.x, (_Float16)c.y};
            wn_[i] = (f16x2){(_Float16)d.x, (_Float16)d.y};
        }
    }
    const float bn_ = bhh[j + 2 * HH];   // r/z biases folded into gi

    float hreg = 0.f;
    if (tid < HH) hb[0][tid] = (_Float16)0.f;
    const unsigned short* gb = gi + (size_t)b * SEQ * NG;

    // depth-4 prefetch registers + incremental source pointers
    float gAr, gAz, gAn, gBr, gBz, gBn, gCr, gCz, gCn, gDr, gDz, gDn;
    {
        const unsigned short* g0 = gb;          gAr = bf2f(g0[j]); gAz = bf2f(g0[j+HH]); gAn = bf2f(g0[j+2*HH]);
        const unsigned short* g1 = gb + NG;     gBr = bf2f(g1[j]); gBz = bf2f(g1[j+HH]); gBn = bf2f(g1[j+2*HH]);
        const unsigned short* g2 = gb + 2 * NG; gCr = bf2f(g2[j]); gCz = bf2f(g2[j+HH]); gCn = bf2f(g2[j+2*HH]);
        const unsigned short* g3 = gb + 3 * NG; gDr = bf2f(g3[j]); gDz = bf2f(g3[j+HH]); gDn = bf2f(g3[j+2*HH]);
    }
    const unsigned short* pA = gb + 4 * NG;
    const unsigned short* pB = gb + 5 * NG;
    const unsigned short* pC = gb + 6 * NG;
    const unsigned short* pD = gb + 7 * NG;
    BAR_LDS();

    // NOTE: prefetch in the final iterations reads past gi's end into the
    // spart/hf scratch regions (allocated) — loaded but never consumed.
#define GRU_BODY(P, GR, GZ, GN, PP)                                            \
    {                                                                          \
        float ar[2] = {0.f, 0.f}, az[2] = {0.f, 0.f}, an[2] = {0.f, 0.f};      \
        const uint4* hp = (const uint4*)&hb[P][half * 64];                     \
        _Pragma("unroll")                                                      \
        for (int i = 0; i < 8; ++i) {                                          \
            union { uint4 u; f16x2 h2[4]; } U;                                 \
            U.u = hp[i];                                                       \
            _Pragma("unroll")                                                  \
            for (int k = 0; k < 4; ++k) {                                      \
                ar[k&1] = __builtin_amdgcn_fdot2(wr_[i*4+k], U.h2[k], ar[k&1], false); \
                az[k&1] = __builtin_amdgcn_fdot2(wz_[i*4+k], U.h2[k], az[k&1], false); \
                an[k&1] = __builtin_amdgcn_fdot2(wn_[i*4+k], U.h2[k], an[k&1], false); \
            }                                                                  \
        }                                                                      \
        const float arf = dpp_pair_add(ar[0] + ar[1]);                         \
        const float azf = dpp_pair_add(az[0] + az[1]);                         \
        const float anf = dpp_pair_add(an[0] + an[1]);                         \
        const float r = fsig(GR + arf);                                        \
        const float z = fsig(GZ + azf);                                        \
        const float n = ftanh(GN + r * (anf + bn_));                           \
        hreg = n + z * (hreg - n);                                             \
        if (!half) hb[P ^ 1][j] = (_Float16)hreg;                              \
        GR = bf2f(PP[j]); GZ = bf2f(PP[j + HH]); GN = bf2f(PP[j + 2 * HH]);    \
        PP += 4 * NG;                                                          \
        BAR_LDS();                                                             \
    }

    for (int it = 0; it < SEQ / 4; ++it) {
        GRU_BODY(0, gAr, gAz, gAn, pA)
        GRU_BODY(1, gBr, gBz, gBn, pB)
        GRU_BODY(0, gCr, gCz, gCn, pC)
        GRU_BODY(1, gDr, gDz, gDn, pD)
    }
#undef GRU_BODY
    if (!half) hout[b * HH + j] = hreg;
}

// ---------------------------------------------------------------------------
// fused backward-direction GRU cell + MLP head. Thread j needs exactly
// W_ih_b rows j, j+128, j+256 -> h_bwd[j] computed thread-locally.
// ---------------------------------------------------------------------------
__global__ __launch_bounds__(128) void mlp(const float* __restrict__ X,
                                           const float* __restrict__ mask,
                                           const float* __restrict__ WihB,
                                           const float* __restrict__ bihB,
                                           const float* __restrict__ bhhB,
                                           const float* __restrict__ hf,
                                           const float* __restrict__ spart,
                                           const float* __restrict__ W1, const float* __restrict__ b1,
                                           const float* __restrict__ W2, const float* __restrict__ b2,
                                           const float* __restrict__ W3, const float* __restrict__ b3,
                                           float* __restrict__ out) {
    const int b = blockIdx.x, j = threadIdx.x;
    __shared__ float xl[EMB];
    __shared__ float zin[2 * HH + EMB];   // 556
    __shared__ float l1[128];
    __shared__ float l2[64];

    const float* xr = X + ((size_t)b * SEQ + (SEQ - 1)) * EMB;
    const float  mv = mask[(size_t)b * SEQ + SEQ - 1];
    for (int e = j; e < EMB; e += 128) xl[e] = xr[e];
    zin[j] = hf[b * HH + j];
    for (int e = j; e < EMB; e += 128) {
        float v = 0.f;
        #pragma unroll
        for (int c = 0; c < NCHUNK; ++c)
            v += spart[((size_t)b * NCHUNK + c) * EMB + e];
        zin[2 * HH + e] = v * v;
    }
    __syncthreads();

    // ---- h_bwd[j]: one GRU cell on last token, h0 = 0 ----
    {
        const float* wR = WihB + (size_t)j * EMB;
        const float* wZ = WihB + (size_t)(j + HH) * EMB;
        const float* wN = WihB + (size_t)(j + 2 * HH) * EMB;
        float aR = 0.f, aZ = 0.f, aN = 0.f;
        for (int e = 0; e < EMB; ++e) {
            const float xv = xl[e];
            aR += xv * wR[e]; aZ += xv * wZ[e]; aN += xv * wN[e];
        }
        const float r = fsig(aR * mv + bihB[j] + bhhB[j]);
        const float z = fsig(aZ * mv + bihB[j + HH] + bhhB[j + HH]);
        const float n = ftanh(aN * mv + bihB[j + 2 * HH] + r * bhhB[j + 2 * HH]);
        zin[HH + j] = (1.f - z) * n;
    }
    __syncthreads();

    {
        float a = b1[j];
        const float* w = W1 + (size_t)j * (2 * HH + EMB);
        for (int i = 0; i < 2 * HH + EMB; ++i) a += zin[i] * w[i];
        l1[j] = fmaxf(a, 0.f);
    }
    __syncthreads();
    if (j < 64) {
        float a = b2[j];
        const float* w = W2 + (size_t)j * 128;
        for (int i = 0; i < 128; ++i) a += l1[i] * w[i];
        l2[j] = fmaxf(a, 0.f);
    }
    __syncthreads();
    if (j < 23) {
        float a = b3[j];
        const float* w = W3 + (size_t)j * 64;
        for (int i = 0; i < 64; ++i) a += l2[i] * w[i];
        out[b * 23 + j] = a;
    }
}

// ---------------------------------------------------------------------------
extern "C" void kernel_launch(void* const* d_in, const int* in_sizes, int n_in,
                              void* d_out, int out_size, void* d_ws, size_t ws_size,
                              hipStream_t stream) {
    const float* x     = (const float*)d_in[0];
    const float* mask  = (const float*)d_in[2];
    const float* Wih_f = (const float*)d_in[3];
    const float* Whh_f = (const float*)d_in[4];
    const float* bih_f = (const float*)d_in[5];
    const float* bhh_f = (const float*)d_in[6];
    const float* Wih_b = (const float*)d_in[7];
    const float* bih_b = (const float*)d_in[9];
    const float* bhh_b = (const float*)d_in[10];
    const float* W1 = (const float*)d_in[11];
    const float* b1 = (const float*)d_in[12];
    const float* W2 = (const float*)d_in[13];
    const float* b2 = (const float*)d_in[14];
    const float* W3 = (const float*)d_in[15];
    const float* b3 = (const float*)d_in[16];
    float* out = (float*)d_out;

    unsigned short* gi16 = (unsigned short*)d_ws;              // 64*1024*384 bf16 = 48 MB
    float* spart = (float*)(gi16 + (size_t)BS * SEQ * NG);     // 64*8*300 f32
    float* hf    = spart + (size_t)BS * NCHUNK * EMB;          // 64*128 f32

    gi_gemm<<<dim3(512), dim3(512), 0, stream>>>(x, mask, Wih_f, bih_f, bhh_f, gi16);
    col_sum<<<dim3(BS, NCHUNK), dim3(320), 0, stream>>>(x, mask, spart);
    gru_scan<<<dim3(BS), dim3(256), 0, stream>>>(gi16, Whh_f, bhh_f, hf);
    mlp<<<dim3(BS), dim3(128), 0, stream>>>(x, mask, Wih_b, bih_b, bhh_b, hf, spart,
                                            W1, b1, W2, b2, W3, b3, out);
}